// Round 8
// baseline (177.585 us; speedup 1.0000x reference)
//
#include <hip/hip_runtime.h>

// Problem constants (B, C=1, H, W) from the reference.
#define H_ 1024
#define W_ 1024
#define B_ 16
#define TH 8                   // output rows per block (STEPS=14 fully unrolls; 22 spilled - r3)
#define STEPS (TH + 6)         // input rows streamed (halo 3 each side)
#define GX (H_ / TH)           // 128 y-tiles per image
#define NBLK (GX * B_)         // 2048 blocks
#define NACC 13
#define TW 8                   // cols per thread (transposed algebra: ring state is raw-only -> affordable)
#define BT 128                 // threads per block; BT*TW == W_

// partials layout (SoA): partials[j * NBLK + bid]
//  j: 0=sum_pred, then k=3,5,7: {1,5,9}=sum_dil {2,6,10}=sum_p*dil
//                               {3,7,11}=sum_ero {4,8,12}=sum_p*ero

// Transposed elliptical-morphology decomposition (exact transpose of the
// r2-verified row split; ellipse is xy-symmetric):
//   V3[x] = op(r[y-1..y+1][x]); V5[x] = op(V3[x], r[y-2][x], r[y+2][x]);
//   V7[x] = op(V5[x], r[y-3][x], r[y+3][x])
//   k3 = op(V3[x],  r0[x+/-1])
//   k5 = op(V5[x],  V3[x+/-1], r0[x+/-2])
//   k7 = op(V7[x],  V5[x+/-1], V5[x+/-2], r0[x+/-3])
// Live state = ONE raw 7-row ring (shared by dil+ero) -> 8 cols/thread fits.
// Geodesic (exclude-OOB) border == clamped-index border (clamped taps
// duplicate values in a superset window part) -> exact (r2/r5-verified).
__global__ __launch_bounds__(BT) void k_partials(const float* __restrict__ pred,
                                                 const float* __restrict__ tch,
                                                 float* __restrict__ partials) {
  const int tid = threadIdx.x;
  // XCD swizzle (r6/r7: FETCH 90->67MB): same-XCD-consecutive blocks get
  // consecutive y-tiles -> halo rows hit that XCD's L2.
  const int n     = blockIdx.y * gridDim.x + blockIdx.x;
  const int b     = n >> 7;                              // image (gridDim.x == 128)
  const int ytile = (n & 7) * 16 + ((n >> 3) & 15);      // bijective 0..127
  const int y0    = ytile * TH;
  const int x0    = tid * TW;
  const float* tb = tch  + (size_t)b * (H_ * W_);
  const float* pb = pred + (size_t)b * (H_ * W_);

  float acc[NACC];
#pragma unroll
  for (int j = 0; j < NACC; j++) acc[j] = 0.f;

  // raw ring: rows (y-3..y+3) x cols (x0-4 .. x0+11); i = col - (x0-4)
  float ring[7][16];

#pragma unroll
  for (int s = 0; s < STEPS; ++s) {
    // ---- load teacher row y0+s-3 (y-clamped) into ring slot s%7
    {
      const int t    = y0 + s - 3;
      const int trow = t < 0 ? 0 : (t >= H_ ? H_ - 1 : t);
      const float* tr = tb + (size_t)trow * W_ + x0;
      const float4 v1 = *reinterpret_cast<const float4*>(tr);
      const float4 v2 = *reinterpret_cast<const float4*>(tr + 4);
      ring[s % 7][4]  = v1.x; ring[s % 7][5]  = v1.y; ring[s % 7][6]  = v1.z; ring[s % 7][7]  = v1.w;
      ring[s % 7][8]  = v2.x; ring[s % 7][9]  = v2.y; ring[s % 7][10] = v2.z; ring[s % 7][11] = v2.w;
      if (tid > 0) {
        const float4 vl = *reinterpret_cast<const float4*>(tr - 4);
        ring[s % 7][0] = vl.x; ring[s % 7][1] = vl.y; ring[s % 7][2] = vl.z; ring[s % 7][3] = vl.w;
      } else {                      // x-clamp left (exact)
        ring[s % 7][0] = ring[s % 7][1] = ring[s % 7][2] = ring[s % 7][3] = v1.x;
      }
      if (tid < BT - 1) {
        const float4 vr = *reinterpret_cast<const float4*>(tr + 8);
        ring[s % 7][12] = vr.x; ring[s % 7][13] = vr.y; ring[s % 7][14] = vr.z; ring[s % 7][15] = vr.w;
      } else {                      // x-clamp right (exact)
        ring[s % 7][12] = ring[s % 7][13] = ring[s % 7][14] = ring[s % 7][15] = v2.w;
      }
    }

    // ---- emit output row y = y0+s-6 (ring now holds rows y-3..y+3)
    if (s >= 6) {
      // ring slots: row y+d  ->  ring[(s + 7 + (d+3) - 6) % 7]  (loaded at step s-3+d... wait: row y+d loaded at step (y+d)-y0+3 = s-3+d -> slot (s+4+d)%7)
      // d=-3:(s+1)%7  d=-2:(s+2)%7  d=-1:(s+3)%7  d=0:(s+4)%7  d=+1:(s+5)%7  d=+2:(s+6)%7  d=+3:(s)%7
      float V3M[16], V3N[16], V5M[16], V5N[16];
#pragma unroll
      for (int i = 2; i <= 13; ++i) {
        const float rm1 = ring[(s + 3) % 7][i], rc = ring[(s + 4) % 7][i], rp1 = ring[(s + 5) % 7][i];
        V3M[i] = fmaxf(fmaxf(rm1, rc), rp1);                       // v_max3
        V3N[i] = fminf(fminf(rm1, rc), rp1);                       // v_min3
        V5M[i] = fmaxf(fmaxf(V3M[i], ring[(s + 2) % 7][i]), ring[(s + 6) % 7][i]);
        V5N[i] = fminf(fminf(V3N[i], ring[(s + 2) % 7][i]), ring[(s + 6) % 7][i]);
      }
      const float* pr = pb + (size_t)(y0 + s - 6) * W_ + x0;
      const float4 p1 = *reinterpret_cast<const float4*>(pr);
      const float4 p2 = *reinterpret_cast<const float4*>(pr + 4);
      const float p[TW] = {p1.x, p1.y, p1.z, p1.w, p2.x, p2.y, p2.z, p2.w};
#pragma unroll
      for (int c = 0; c < TW; ++c) {
        const int i = c + 4;
        const float V7M = fmaxf(fmaxf(V5M[i], ring[(s + 1) % 7][i]), ring[s % 7][i]);
        const float V7N = fminf(fminf(V5N[i], ring[(s + 1) % 7][i]), ring[s % 7][i]);

        const float d3 = fmaxf(fmaxf(V3M[i], ring[(s + 4) % 7][i - 1]), ring[(s + 4) % 7][i + 1]);
        const float e3 = fminf(fminf(V3N[i], ring[(s + 4) % 7][i - 1]), ring[(s + 4) % 7][i + 1]);

        float d5 = fmaxf(fmaxf(V5M[i], V3M[i - 1]), V3M[i + 1]);
        d5 = fmaxf(fmaxf(d5, ring[(s + 4) % 7][i - 2]), ring[(s + 4) % 7][i + 2]);
        float e5 = fminf(fminf(V5N[i], V3N[i - 1]), V3N[i + 1]);
        e5 = fminf(fminf(e5, ring[(s + 4) % 7][i - 2]), ring[(s + 4) % 7][i + 2]);

        float d7 = fmaxf(fmaxf(V7M, V5M[i - 1]), V5M[i + 1]);
        d7 = fmaxf(fmaxf(d7, V5M[i - 2]), V5M[i + 2]);
        d7 = fmaxf(fmaxf(d7, ring[(s + 4) % 7][i - 3]), ring[(s + 4) % 7][i + 3]);
        float e7 = fminf(fminf(V7N, V5N[i - 1]), V5N[i + 1]);
        e7 = fminf(fminf(e7, V5N[i - 2]), V5N[i + 2]);
        e7 = fminf(fminf(e7, ring[(s + 4) % 7][i - 3]), ring[(s + 4) % 7][i + 3]);

        acc[0]  += p[c];
        acc[1]  += d3;  acc[2]  = fmaf(p[c], d3, acc[2]);
        acc[3]  += e3;  acc[4]  = fmaf(p[c], e3, acc[4]);
        acc[5]  += d5;  acc[6]  = fmaf(p[c], d5, acc[6]);
        acc[7]  += e5;  acc[8]  = fmaf(p[c], e5, acc[8]);
        acc[9]  += d7;  acc[10] = fmaf(p[c], d7, acc[10]);
        acc[11] += e7;  acc[12] = fmaf(p[c], e7, acc[12]);
      }
    }
  }

  // wave (64-lane) shuffle reduction, then cross-wave (2 waves) via LDS
#pragma unroll
  for (int j = 0; j < NACC; j++) {
    float v = acc[j];
#pragma unroll
    for (int off = 32; off > 0; off >>= 1) v += __shfl_down(v, off, 64);
    acc[j] = v;
  }
  __shared__ float red[2][NACC];
  const int lane = tid & 63, wv = tid >> 6;
  if (lane == 0) {
#pragma unroll
    for (int j = 0; j < NACC; j++) red[wv][j] = acc[j];
  }
  __syncthreads();
  if (tid == 0) {
#pragma unroll
    for (int j = 0; j < NACC; j++)
      partials[j * NBLK + n] = red[0][j] + red[1][j];
  }
}

__global__ __launch_bounds__(256) void k_final(const float* __restrict__ partials,
                                               float* __restrict__ out) {
  const int tid = threadIdx.x;
  double acc[NACC];
#pragma unroll
  for (int j = 0; j < NACC; j++) acc[j] = 0.0;
#pragma unroll
  for (int k = 0; k < NBLK / 256; k++) {
#pragma unroll
    for (int j = 0; j < NACC; j++)
      acc[j] += (double)partials[j * NBLK + tid + k * 256];   // coalesced, independent
  }
#pragma unroll
  for (int j = 0; j < NACC; j++) {
#pragma unroll
    for (int off = 32; off > 0; off >>= 1) acc[j] += __shfl_down(acc[j], off, 64);
  }
  __shared__ double red[4][NACC];
  const int lane = tid & 63, wv = tid >> 6;
  if (lane == 0) {
#pragma unroll
    for (int j = 0; j < NACC; j++) red[wv][j] = acc[j];
  }
  __syncthreads();
  if (tid == 0) {
    double t_[NACC];
#pragma unroll
    for (int j = 0; j < NACC; j++) t_[j] = red[0][j] + red[1][j] + red[2][j] + red[3][j];
    const double Sp = t_[0];
    double total = 0.0;
#pragma unroll
    for (int k = 0; k < 3; k++) {
      const double Sd = t_[1 + 4 * k], Id = t_[2 + 4 * k];
      const double Se = t_[3 + 4 * k], Ie = t_[4 + 4 * k];
      double cd = Sp + Sd; if (cd < 1e-7) cd = 1e-7;
      double ce = Sp + Se; if (ce < 1e-7) ce = 1e-7;
      total += (1.0 - 2.0 * Id / cd) * (Sd > 0.0 ? 1.0 : 0.0);
      total += (1.0 - 2.0 * Ie / ce) * (Se > 0.0 ? 1.0 : 0.0);
    }
    out[0] = (float)(total / 3.0);
  }
}

extern "C" void kernel_launch(void* const* d_in, const int* in_sizes, int n_in,
                              void* d_out, int out_size, void* d_ws, size_t ws_size,
                              hipStream_t stream) {
  const float* pred = (const float*)d_in[0];  // pred_student_prob
  const float* tch  = (const float*)d_in[1];  // teacher_prob
  float* partials = (float*)d_ws;             // NACC * NBLK floats; fully written each launch

  k_partials<<<dim3(GX, B_), BT, 0, stream>>>(pred, tch, partials);
  k_final<<<1, 256, 0, stream>>>(partials, (float*)d_out);
}